// Round 4
// baseline (652.950 us; speedup 1.0000x reference)
//
#include <hip/hip_runtime.h>
#include <math.h>

// Problem constants
#define B_   64
#define T_   256
#define W_   20
#define NP_  6
#define NT_  12
#define CC_  32      // CONV_CH
#define FD_  8       // FRAG_DIM
#define PR_  64      // PROJ

typedef float v2f __attribute__((ext_vector_type(2)));

// Pin a value into a VGPR: the asm is an opaque, non-rematerializable def,
// so the register allocator cannot sink the original load into the loop.
#define PIN2(x) asm volatile("" : "+v"(x))

__device__ __forceinline__ float sigmoidf_(float x) {
    return 1.0f / (1.0f + __expf(-x));
}
__device__ __forceinline__ float tanhf_(float x) {
    x = fminf(fmaxf(x, -15.0f), 15.0f);
    float e = __expf(2.0f * x);
    return (e - 1.0f) / (e + 1.0f);
}

// -------------------------------------------------------------------------
// Kernel 1: per-window encoders + fragility + projection + LSTM input gates.
// One wave per (b,t) window; 16384 blocks.
// Changes this round: conv2 weights live in LDS (rows padded to 97 floats ->
// 64 lanes map 2/bank = conflict-free), conv2 i-loop only unroll-4 so the
// compiler can't hoist 160 loads, __launch_bounds__(64,2) caps VGPR at 256.
// -------------------------------------------------------------------------
__global__ __launch_bounds__(64, 2) void encoder_kernel(
    const float* __restrict__ pressure, const float* __restrict__ torque,
    const float* __restrict__ frag,
    const float* __restrict__ pw1, const float* __restrict__ pb1,
    const float* __restrict__ pw2, const float* __restrict__ pb2,
    const float* __restrict__ tw1, const float* __restrict__ tb1,
    const float* __restrict__ tw2, const float* __restrict__ tb2,
    const float* __restrict__ fw,  const float* __restrict__ fb,
    const float* __restrict__ prw, const float* __restrict__ prb,
    const float* __restrict__ Wih, const float* __restrict__ bih,
    const float* __restrict__ bhh,
    float* __restrict__ xg)             // (B,T,256) output
{
    const int bt  = blockIdx.x;         // 0..16383
    const int b   = bt >> 8;            // T_=256
    const int tid = threadIdx.x;        // 0..63
    const int  o   = tid & 31;
    const bool isp = tid < 32;

    __shared__ __align__(16) float xwin[360];    // pressure 6x20 | torque 12x20
    __shared__ __align__(16) float h1[1280];     // h1p 32x20 | h1t 32x20
    __shared__ __align__(16) float catb[72];     // pf(32) | tf(32) | ff(8)
    __shared__ __align__(16) float featsh[64];
    __shared__ float w2lds[64 * 97];             // conv2 weights, row-padded to 97

    // ---- stage conv2 weights into LDS (coalesced reads; rows of 96 -> 97) ----
    for (int idx = tid; idx < CC_ * 96; idx += 64) {
        int row = idx / 96, col = idx - row * 96;
        w2lds[row * 97 + col] = pw2[idx];
    }
    for (int idx = tid; idx < CC_ * 96; idx += 64) {
        int row = idx / 96, col = idx - row * 96;
        w2lds[(32 + row) * 97 + col] = tw2[idx];
    }

    // ---- preload conv1 weights into registers, zero-padded to 12 input rows ----
    float w1r[36];
    {
        const float* w1 = isp ? (pw1 + o * (NP_ * 3)) : (tw1 + o * (NT_ * 3));
        const int n3 = (isp ? NP_ : NT_) * 3;
        #pragma unroll
        for (int k = 0; k < 36; ++k) w1r[k] = (k < n3) ? w1[k] : 0.0f;
    }
    const float bz1 = isp ? pb1[o] : tb1[o];
    const float bz2 = isp ? pb2[o] : tb2[o];

    // ---- stage window, transposing [w][i] -> [i][w] ----
    const float* pin = pressure + (size_t)bt * (W_ * NP_);
    for (int idx = tid; idx < W_ * NP_; idx += 64) {
        int w = idx / NP_, i = idx - w * NP_;
        xwin[i * 20 + w] = pin[idx];
    }
    const float* tin = torque + (size_t)bt * (W_ * NT_);
    for (int idx = tid; idx < W_ * NT_; idx += 64) {
        int w = idx / NT_, i = idx - w * NT_;
        xwin[120 + i * 20 + w] = tin[idx];
    }
    if (tid < FD_) catb[64 + tid] = fmaxf(frag[b] * fw[tid] + fb[tid], 0.0f);
    __syncthreads();

    // ---- conv1 (valid, K=3): uniform 12-row loop, weights in regs ----
    {
        const float* xin = xwin + (isp ? 0 : 120);
        float acc[18];
        #pragma unroll
        for (int l = 0; l < 18; ++l) acc[l] = bz1;
        #pragma unroll
        for (int i = 0; i < 12; ++i) {
            float4 xr4[5];
            const float4* xrow = (const float4*)(xin + i * 20);
            #pragma unroll
            for (int q = 0; q < 5; ++q) xr4[q] = xrow[q];     // broadcast b128
            const float* xr = (const float*)xr4;
            const float wk0 = w1r[i * 3 + 0], wk1 = w1r[i * 3 + 1], wk2 = w1r[i * 3 + 2];
            #pragma unroll
            for (int l = 0; l < 18; ++l)
                acc[l] += xr[l] * wk0 + xr[l + 1] * wk1 + xr[l + 2] * wk2;
        }
        float* h1o = h1 + (isp ? 0 : 640) + o * 20;
        #pragma unroll
        for (int l = 0; l < 18; ++l) h1o[l] = fmaxf(acc[l], 0.0f);
    }
    __syncthreads();

    // ---- conv2 (32->32, K=3) + relu + mean; weights from LDS, unroll-4 ----
    {
        const float* h1i  = h1 + (isp ? 0 : 640);
        const float* w2row = w2lds + tid * 97;   // lane's 96 weights (2/bank)
        float s[16];
        #pragma unroll
        for (int l = 0; l < 16; ++l) s[l] = bz2;
        #pragma unroll 4
        for (int i = 0; i < 32; ++i) {
            float4 hr4[5];
            const float4* hrow = (const float4*)(h1i + i * 20);
            #pragma unroll
            for (int q = 0; q < 5; ++q) hr4[q] = hrow[q];     // broadcast b128
            const float* hr = (const float*)hr4;
            const float wk0 = w2row[i * 3 + 0], wk1 = w2row[i * 3 + 1], wk2 = w2row[i * 3 + 2];
            #pragma unroll
            for (int l = 0; l < 16; ++l)
                s[l] += hr[l] * wk0 + hr[l + 1] * wk1 + hr[l + 2] * wk2;
        }
        float m = 0.0f;
        #pragma unroll
        for (int l = 0; l < 16; ++l) m += fmaxf(s[l], 0.0f);
        catb[tid] = m * 0.0625f;
    }
    __syncthreads();

    // ---- projection 72 -> 64, relu ----
    {
        float acc = prb[tid];
        const float4* w4 = (const float4*)(prw + tid * 72);
        const float4* c4 = (const float4*)catb;
        #pragma unroll
        for (int q = 0; q < 18; ++q) {
            float4 w = w4[q], cv = c4[q];
            acc += w.x * cv.x + w.y * cv.y + w.z * cv.z + w.w * cv.w;
        }
        featsh[tid] = fmaxf(acc, 0.0f);
    }
    __syncthreads();

    // ---- xg = feat @ Wih.T + bih + bhh ----
    {
        float4 fr[16];
        const float4* f4 = (const float4*)featsh;
        #pragma unroll
        for (int q = 0; q < 16; ++q) fr[q] = f4[q];
        float* xgrow = xg + (size_t)bt * 256;
        #pragma unroll
        for (int gi = 0; gi < 4; ++gi) {
            const int g = tid + 64 * gi;
            const float4* w4 = (const float4*)(Wih + (size_t)g * 64);
            float acc = bih[g] + bhh[g];
            #pragma unroll
            for (int q = 0; q < 16; ++q) {
                float4 w = w4[q];
                acc += w.x * fr[q].x + w.y * fr[q].y + w.z * fr[q].z + w.w * fr[q].w;
            }
            xgrow[g] = acc;
        }
    }
}

// -------------------------------------------------------------------------
// Kernel 2: LSTM recurrence — single wave per batch element, 1 wave/SIMD.
// Weights are PINNED into VGPRs via asm so the allocator cannot sink the
// loads back into the T-loop (rounds 2/3 failure mode: VGPR_Count=148-152,
// weights re-fetched every step).
// -------------------------------------------------------------------------
__global__ __launch_bounds__(64, 1) void lstm_kernel(
    const float* __restrict__ xg,     // (B,T,256), bias already included
    const float* __restrict__ Whh,    // (256,64)
    float* __restrict__ hout,         // (B,T,64)
    float* __restrict__ dout)         // full output buffer
{
    const int b   = blockIdx.x;
    const int tid = threadIdx.x;      // hidden unit index

    __shared__ __align__(16) float hs[64];

    // 4 Whh rows for this unit (i,f,g,o), 32 float2 each -> 256 VGPRs, pinned
    v2f wi[32], wf[32], wg[32], wo[32];
    {
        const v2f* ri = (const v2f*)(Whh + (size_t)(tid)       * 64);
        const v2f* rf = (const v2f*)(Whh + (size_t)(64  + tid) * 64);
        const v2f* rg = (const v2f*)(Whh + (size_t)(128 + tid) * 64);
        const v2f* ro = (const v2f*)(Whh + (size_t)(192 + tid) * 64);
        #pragma unroll
        for (int q = 0; q < 32; ++q) { wi[q] = ri[q]; wf[q] = rf[q]; wg[q] = rg[q]; wo[q] = ro[q]; }
        #pragma unroll
        for (int q = 0; q < 32; ++q) { PIN2(wi[q]); PIN2(wf[q]); PIN2(wg[q]); PIN2(wo[q]); }
    }

    const float* xgrow = xg + (size_t)b * T_ * 256;
    float* hrow = hout + (size_t)b * T_ * 64;

    float c = 0.0f;
    hs[tid] = 0.0f;
    __syncthreads();

    // 2-deep xg prefetch pipeline
    float xc0 = xgrow[tid], xc1 = xgrow[64 + tid], xc2 = xgrow[128 + tid], xc3 = xgrow[192 + tid];
    float xn0 = xgrow[256 + tid], xn1 = xgrow[320 + tid], xn2 = xgrow[384 + tid], xn3 = xgrow[448 + tid];

    for (int t = 0; t < T_; ++t) {
        const int tp = (t + 2 < T_) ? (t + 2) : (T_ - 1);
        const float* xpf = xgrow + tp * 256 + tid;
        float xf0 = xpf[0], xf1 = xpf[64], xf2 = xpf[128], xf3 = xpf[192];

        // 4-gate matvec slice, float2-packed: 128 pk-FMAs
        v2f ai = {xc0, 0.0f}, af = {xc1, 0.0f}, ag = {xc2, 0.0f}, ao = {xc3, 0.0f};
        const v2f* h2 = (const v2f*)hs;
        #pragma unroll
        for (int q = 0; q < 32; ++q) {
            v2f hv = h2[q];                      // wave-uniform broadcast read
            ai += wi[q] * hv;
            af += wf[q] * hv;
            ag += wg[q] * hv;
            ao += wo[q] * hv;
        }

        const float I = sigmoidf_(ai.x + ai.y);
        const float F = sigmoidf_(af.x + af.y);
        const float G = tanhf_(ag.x + ag.y);
        const float O = sigmoidf_(ao.x + ao.y);
        c = F * c + I * G;
        const float h = O * tanhf_(c);

        __syncthreads();              // single-wave: waitcnt drain only
        hs[tid] = h;
        hrow[t * 64 + tid] = h;       // coalesced 256B store
        __syncthreads();

        xc0 = xn0; xc1 = xn1; xc2 = xn2; xc3 = xn3;
        xn0 = xf0; xn1 = xf1; xn2 = xf2; xn3 = xf3;
    }

    dout[B_ * T_ * 4 + b * 64 + tid]           = hs[tid];  // hT
    dout[B_ * T_ * 4 + B_ * 64 + b * 64 + tid] = c;        // cT
}

// -------------------------------------------------------------------------
// Kernel 3: head (unchanged).
// -------------------------------------------------------------------------
__global__ __launch_bounds__(256) void head_kernel(
    const float* __restrict__ hout, const float* __restrict__ hw,
    const float* __restrict__ hb, float* __restrict__ out)
{
    const int blk = blockIdx.x;
    const int tid = threadIdx.x;

    __shared__ __align__(16) float hsh[64 * 68];
    __shared__ __align__(16) float wsh[256];
    __shared__ float bsh[4];

    const float4* s4 = (const float4*)(hout + (size_t)blk * 64 * 64);
    float4* d4 = (float4*)hsh;
    for (int q = tid; q < 1024; q += 256) {
        int row = q >> 4, col = q & 15;
        d4[row * 17 + col] = s4[q];
    }
    if (tid < 64) ((float4*)wsh)[tid] = ((const float4*)hw)[tid];
    if (tid < 4)  bsh[tid] = hb[tid];
    __syncthreads();

    const int r = tid >> 2, m = tid & 3;
    const float4* hv = (const float4*)(hsh + r * 68);
    const float4* wv = (const float4*)(wsh + m * 64);
    float acc = bsh[m];
    #pragma unroll
    for (int q = 0; q < 16; ++q) {
        float4 a = hv[q], w = wv[q];
        acc += a.x * w.x + a.y * w.y + a.z * w.z + a.w * w.w;
    }
    out[(size_t)blk * 256 + tid] = sigmoidf_(acc);
}

extern "C" void kernel_launch(void* const* d_in, const int* in_sizes, int n_in,
                              void* d_out, int out_size, void* d_ws, size_t ws_size,
                              hipStream_t stream) {
    const float* pressure = (const float*)d_in[0];
    const float* torque   = (const float*)d_in[1];
    const float* frag     = (const float*)d_in[2];
    const float* pw1 = (const float*)d_in[3];
    const float* pb1 = (const float*)d_in[4];
    const float* pw2 = (const float*)d_in[5];
    const float* pb2 = (const float*)d_in[6];
    const float* tw1 = (const float*)d_in[7];
    const float* tb1 = (const float*)d_in[8];
    const float* tw2 = (const float*)d_in[9];
    const float* tb2 = (const float*)d_in[10];
    const float* fw  = (const float*)d_in[11];
    const float* fb  = (const float*)d_in[12];
    const float* prw = (const float*)d_in[13];
    const float* prb = (const float*)d_in[14];
    const float* Wih = (const float*)d_in[15];
    const float* Whh = (const float*)d_in[16];
    const float* bih = (const float*)d_in[17];
    const float* bhh = (const float*)d_in[18];
    const float* hw  = (const float*)d_in[19];
    const float* hb  = (const float*)d_in[20];

    float* out = (float*)d_out;

    // workspace: xg (B*T*256 f32 = 16 MB) | hout (B*T*64 f32 = 4 MB)
    float* xg   = (float*)d_ws;
    float* hout = xg + (size_t)B_ * T_ * 256;

    encoder_kernel<<<B_ * T_, 64, 0, stream>>>(
        pressure, torque, frag,
        pw1, pb1, pw2, pb2, tw1, tb1, tw2, tb2,
        fw, fb, prw, prb, Wih, bih, bhh, xg);

    lstm_kernel<<<B_, 64, 0, stream>>>(xg, Whh, hout, out);

    head_kernel<<<B_ * T_ / 64, 256, 0, stream>>>(hout, hw, hb, out);
}

// Round 5
// 628.794 us; speedup vs baseline: 1.0384x; 1.0384x over previous
//
#include <hip/hip_runtime.h>
#include <math.h>

// Problem constants
#define B_   64
#define T_   256
#define W_   20
#define NP_  6
#define NT_  12
#define CC_  32      // CONV_CH
#define FD_  8       // FRAG_DIM
#define PR_  64      // PROJ

typedef float v2f __attribute__((ext_vector_type(2)));

// Pin a value into a VGPR (opaque def, not rematerializable as a load).
#define PIN2(x) asm volatile("" : "+v"(x))
// Wave-local LDS ordering: drain LDS/SMEM ops, compiler memory barrier.
// NO vmcnt drain, NO s_barrier -> global loads/stores stay in flight.
#define WAVE_SYNC() asm volatile("s_waitcnt lgkmcnt(0)" ::: "memory")

__device__ __forceinline__ float sigmoidf_(float x) {
    return 1.0f / (1.0f + __expf(-x));
}
__device__ __forceinline__ float tanhf_(float x) {
    x = fminf(fmaxf(x, -15.0f), 15.0f);
    float e = __expf(2.0f * x);
    return (e - 1.0f) / (e + 1.0f);
}

// -------------------------------------------------------------------------
// Kernel 1: encoders + fragility + projection + LSTM input-gate precompute.
// 4096 blocks x 256 threads; wave w handles window blockIdx*4+w.
// conv2 weights staged ONCE per block into shared w2lds (amortized 4x);
// per-wave phases use WAVE_SYNC (no vmcnt drain) — only ONE real barrier.
// LDS/block ~53 KB -> 3 blocks/CU = 12 waves/CU (vs 5 in round 4).
// -------------------------------------------------------------------------
__global__ __launch_bounds__(256, 3) void encoder_kernel(
    const float* __restrict__ pressure, const float* __restrict__ torque,
    const float* __restrict__ frag,
    const float* __restrict__ pw1, const float* __restrict__ pb1,
    const float* __restrict__ pw2, const float* __restrict__ pb2,
    const float* __restrict__ tw1, const float* __restrict__ tb1,
    const float* __restrict__ tw2, const float* __restrict__ tb2,
    const float* __restrict__ fw,  const float* __restrict__ fb,
    const float* __restrict__ prw, const float* __restrict__ prb,
    const float* __restrict__ Wih, const float* __restrict__ bih,
    const float* __restrict__ bhh,
    float* __restrict__ xg)             // (B,T,256) output
{
    const int tid  = threadIdx.x;       // 0..255
    const int wv   = tid >> 6;          // wave 0..3
    const int lane = tid & 63;
    const int bt   = blockIdx.x * 4 + wv;   // window id
    const int b    = bt >> 8;
    const int  o   = lane & 31;
    const bool isp = lane < 32;

    __shared__ float w2lds[64 * 97];                 // 24832 B, shared by all waves
    __shared__ __align__(16) float xwin4[4][360];    // per-wave window
    __shared__ __align__(16) float h14[4][1280];     // per-wave conv1 out
    __shared__ __align__(16) float catb4[4][72];
    __shared__ __align__(16) float featsh4[4][64];

    float* xwin   = xwin4[wv];
    float* h1     = h14[wv];
    float* catb   = catb4[wv];
    float* featsh = featsh4[wv];

    // ---- stage conv2 weights once per block (coalesced, rows 96 -> 97) ----
    for (int idx = tid; idx < CC_ * 96; idx += 256) {
        int row = idx / 96, col = idx - row * 96;
        w2lds[row * 97 + col] = pw2[idx];
    }
    for (int idx = tid; idx < CC_ * 96; idx += 256) {
        int row = idx / 96, col = idx - row * 96;
        w2lds[(32 + row) * 97 + col] = tw2[idx];
    }

    // ---- conv1 weights in regs, zero-padded to uniform 12 input rows ----
    float w1r[36];
    {
        const float* w1 = isp ? (pw1 + o * (NP_ * 3)) : (tw1 + o * (NT_ * 3));
        const int n3 = (isp ? NP_ : NT_) * 3;
        #pragma unroll
        for (int k = 0; k < 36; ++k) w1r[k] = (k < n3) ? w1[k] : 0.0f;
    }
    const float bz1 = isp ? pb1[o] : tb1[o];
    const float bz2 = isp ? pb2[o] : tb2[o];

    // ---- stage own window, transposing [w][i] -> [i][w] ----
    const float* pin = pressure + (size_t)bt * (W_ * NP_);
    for (int idx = lane; idx < W_ * NP_; idx += 64) {
        int w = idx / NP_, i = idx - w * NP_;
        xwin[i * 20 + w] = pin[idx];
    }
    const float* tin = torque + (size_t)bt * (W_ * NT_);
    for (int idx = lane; idx < W_ * NT_; idx += 64) {
        int w = idx / NT_, i = idx - w * NT_;
        xwin[120 + i * 20 + w] = tin[idx];
    }
    if (lane < FD_) catb[64 + lane] = fmaxf(frag[b] * fw[lane] + fb[lane], 0.0f);
    WAVE_SYNC();    // xwin visible within the wave (no vmcnt drain)

    // ---- conv1 (valid, K=3): uniform 12-row loop, weights in regs ----
    {
        const float* xin = xwin + (isp ? 0 : 120);
        float acc[18];
        #pragma unroll
        for (int l = 0; l < 18; ++l) acc[l] = bz1;
        #pragma unroll
        for (int i = 0; i < 12; ++i) {
            float4 xr4[5];
            const float4* xrow = (const float4*)(xin + i * 20);
            #pragma unroll
            for (int q = 0; q < 5; ++q) xr4[q] = xrow[q];     // broadcast b128
            const float* xr = (const float*)xr4;
            const float wk0 = w1r[i * 3 + 0], wk1 = w1r[i * 3 + 1], wk2 = w1r[i * 3 + 2];
            #pragma unroll
            for (int l = 0; l < 18; ++l)
                acc[l] += xr[l] * wk0 + xr[l + 1] * wk1 + xr[l + 2] * wk2;
        }
        float* h1o = h1 + (isp ? 0 : 640) + o * 20;
        #pragma unroll
        for (int l = 0; l < 18; ++l) h1o[l] = fmaxf(acc[l], 0.0f);
    }
    __syncthreads();   // the ONE real barrier: w2lds (cross-wave) + h1 ready

    // ---- conv2 (32->32, K=3) + relu + mean; weights from shared LDS ----
    {
        const float* h1i   = h1 + (isp ? 0 : 640);
        const float* w2row = w2lds + lane * 97;   // lane-distinct, 2/bank = free
        float s[16];
        #pragma unroll
        for (int l = 0; l < 16; ++l) s[l] = bz2;
        #pragma unroll 4
        for (int i = 0; i < 32; ++i) {
            float4 hr4[5];
            const float4* hrow = (const float4*)(h1i + i * 20);
            #pragma unroll
            for (int q = 0; q < 5; ++q) hr4[q] = hrow[q];     // broadcast b128
            const float* hr = (const float*)hr4;
            const float wk0 = w2row[i * 3 + 0], wk1 = w2row[i * 3 + 1], wk2 = w2row[i * 3 + 2];
            #pragma unroll
            for (int l = 0; l < 16; ++l)
                s[l] += hr[l] * wk0 + hr[l + 1] * wk1 + hr[l + 2] * wk2;
        }
        float m = 0.0f;
        #pragma unroll
        for (int l = 0; l < 16; ++l) m += fmaxf(s[l], 0.0f);
        catb[lane] = m * 0.0625f;
    }
    WAVE_SYNC();    // catb visible within the wave

    // ---- projection 72 -> 64, relu ----
    {
        float acc = prb[lane];
        const float4* w4 = (const float4*)(prw + lane * 72);
        const float4* c4 = (const float4*)catb;
        #pragma unroll
        for (int q = 0; q < 18; ++q) {
            float4 w = w4[q], cv = c4[q];
            acc += w.x * cv.x + w.y * cv.y + w.z * cv.z + w.w * cv.w;
        }
        featsh[lane] = fmaxf(acc, 0.0f);
    }
    WAVE_SYNC();    // featsh visible within the wave

    // ---- xg = feat @ Wih.T + bih + bhh ----
    {
        float4 fr[16];
        const float4* f4 = (const float4*)featsh;
        #pragma unroll
        for (int q = 0; q < 16; ++q) fr[q] = f4[q];
        float* xgrow = xg + (size_t)bt * 256;
        #pragma unroll
        for (int gi = 0; gi < 4; ++gi) {
            const int g = lane + 64 * gi;
            const float4* w4 = (const float4*)(Wih + (size_t)g * 64);
            float acc = bih[g] + bhh[g];
            #pragma unroll
            for (int q = 0; q < 16; ++q) {
                float4 w = w4[q];
                acc += w.x * fr[q].x + w.y * fr[q].y + w.z * fr[q].z + w.w * fr[q].w;
            }
            xgrow[g] = acc;
        }
    }
}

// -------------------------------------------------------------------------
// Kernel 2: LSTM recurrence — single wave per batch element, NO BARRIERS in
// the T-loop. Rounds 1-4 all stalled ~2600 cyc/step because __syncthreads
// forces `s_waitcnt vmcnt(0)` before s_barrier: the hrow store + xg prefetch
// had to COMPLETE every step. A single wave only needs lgkmcnt ordering for
// the hs write->read round trip; stores/prefetches now pipeline across steps.
// -------------------------------------------------------------------------
__global__ __launch_bounds__(64, 1) void lstm_kernel(
    const float* __restrict__ xg,     // (B,T,256), bias already included
    const float* __restrict__ Whh,    // (256,64)
    float* __restrict__ hout,         // (B,T,64)
    float* __restrict__ dout)         // full output buffer
{
    const int b   = blockIdx.x;
    const int tid = threadIdx.x;      // hidden unit index

    __shared__ __align__(16) float hs[64];

    // 4 Whh rows for this unit (i,f,g,o), 32 float2 each -> 256 VGPRs, pinned
    v2f wi[32], wf[32], wg[32], wo[32];
    {
        const v2f* ri = (const v2f*)(Whh + (size_t)(tid)       * 64);
        const v2f* rf = (const v2f*)(Whh + (size_t)(64  + tid) * 64);
        const v2f* rg = (const v2f*)(Whh + (size_t)(128 + tid) * 64);
        const v2f* ro = (const v2f*)(Whh + (size_t)(192 + tid) * 64);
        #pragma unroll
        for (int q = 0; q < 32; ++q) { wi[q] = ri[q]; wf[q] = rf[q]; wg[q] = rg[q]; wo[q] = ro[q]; }
        #pragma unroll
        for (int q = 0; q < 32; ++q) { PIN2(wi[q]); PIN2(wf[q]); PIN2(wg[q]); PIN2(wo[q]); }
    }

    const float* xgrow = xg + (size_t)b * T_ * 256;
    float* hrow = hout + (size_t)b * T_ * 64;

    float c = 0.0f;
    hs[tid] = 0.0f;
    WAVE_SYNC();

    // 2-deep xg prefetch pipeline (loads can now stay in flight across steps)
    float xc0 = xgrow[tid], xc1 = xgrow[64 + tid], xc2 = xgrow[128 + tid], xc3 = xgrow[192 + tid];
    float xn0 = xgrow[256 + tid], xn1 = xgrow[320 + tid], xn2 = xgrow[384 + tid], xn3 = xgrow[448 + tid];

    for (int t = 0; t < T_; ++t) {
        const int tp = (t + 2 < T_) ? (t + 2) : (T_ - 1);
        const float* xpf = xgrow + tp * 256 + tid;
        float xf0 = xpf[0], xf1 = xpf[64], xf2 = xpf[128], xf3 = xpf[192];

        // 4-gate matvec slice, float2-packed FMAs; h read as 16 x b128
        v2f ai = {xc0, 0.0f}, af = {xc1, 0.0f}, ag = {xc2, 0.0f}, ao = {xc3, 0.0f};
        const float4* h4 = (const float4*)hs;
        #pragma unroll
        for (int q = 0; q < 16; ++q) {
            float4 hv4 = h4[q];                  // wave-uniform broadcast read
            v2f hlo = {hv4.x, hv4.y}, hhi = {hv4.z, hv4.w};
            ai += wi[2*q] * hlo + wi[2*q+1] * hhi;
            af += wf[2*q] * hlo + wf[2*q+1] * hhi;
            ag += wg[2*q] * hlo + wg[2*q+1] * hhi;
            ao += wo[2*q] * hlo + wo[2*q+1] * hhi;
        }

        const float I = sigmoidf_(ai.x + ai.y);
        const float F = sigmoidf_(af.x + af.y);
        const float G = tanhf_(ag.x + ag.y);
        const float O = sigmoidf_(ao.x + ao.y);
        c = F * c + I * G;
        const float h = O * tanhf_(c);
        // all hs reads of this step already consumed (data dep) -> safe to write

        hs[tid] = h;
        hrow[t * 64 + tid] = h;       // store pipelines; never drained in-loop
        WAVE_SYNC();                  // hs write visible before next step's reads

        xc0 = xn0; xc1 = xn1; xc2 = xn2; xc3 = xn3;
        xn0 = xf0; xn1 = xf1; xn2 = xf2; xn3 = xf3;
    }

    dout[B_ * T_ * 4 + b * 64 + tid]           = hs[tid];  // hT
    dout[B_ * T_ * 4 + B_ * 64 + b * 64 + tid] = c;        // cT
}

// -------------------------------------------------------------------------
// Kernel 3: head (unchanged).
// -------------------------------------------------------------------------
__global__ __launch_bounds__(256) void head_kernel(
    const float* __restrict__ hout, const float* __restrict__ hw,
    const float* __restrict__ hb, float* __restrict__ out)
{
    const int blk = blockIdx.x;
    const int tid = threadIdx.x;

    __shared__ __align__(16) float hsh[64 * 68];
    __shared__ __align__(16) float wsh[256];
    __shared__ float bsh[4];

    const float4* s4 = (const float4*)(hout + (size_t)blk * 64 * 64);
    float4* d4 = (float4*)hsh;
    for (int q = tid; q < 1024; q += 256) {
        int row = q >> 4, col = q & 15;
        d4[row * 17 + col] = s4[q];
    }
    if (tid < 64) ((float4*)wsh)[tid] = ((const float4*)hw)[tid];
    if (tid < 4)  bsh[tid] = hb[tid];
    __syncthreads();

    const int r = tid >> 2, m = tid & 3;
    const float4* hv = (const float4*)(hsh + r * 68);
    const float4* wv = (const float4*)(wsh + m * 64);
    float acc = bsh[m];
    #pragma unroll
    for (int q = 0; q < 16; ++q) {
        float4 a = hv[q], w = wv[q];
        acc += a.x * w.x + a.y * w.y + a.z * w.z + a.w * w.w;
    }
    out[(size_t)blk * 256 + tid] = sigmoidf_(acc);
}

extern "C" void kernel_launch(void* const* d_in, const int* in_sizes, int n_in,
                              void* d_out, int out_size, void* d_ws, size_t ws_size,
                              hipStream_t stream) {
    const float* pressure = (const float*)d_in[0];
    const float* torque   = (const float*)d_in[1];
    const float* frag     = (const float*)d_in[2];
    const float* pw1 = (const float*)d_in[3];
    const float* pb1 = (const float*)d_in[4];
    const float* pw2 = (const float*)d_in[5];
    const float* pb2 = (const float*)d_in[6];
    const float* tw1 = (const float*)d_in[7];
    const float* tb1 = (const float*)d_in[8];
    const float* tw2 = (const float*)d_in[9];
    const float* tb2 = (const float*)d_in[10];
    const float* fw  = (const float*)d_in[11];
    const float* fb  = (const float*)d_in[12];
    const float* prw = (const float*)d_in[13];
    const float* prb = (const float*)d_in[14];
    const float* Wih = (const float*)d_in[15];
    const float* Whh = (const float*)d_in[16];
    const float* bih = (const float*)d_in[17];
    const float* bhh = (const float*)d_in[18];
    const float* hw  = (const float*)d_in[19];
    const float* hb  = (const float*)d_in[20];

    float* out = (float*)d_out;

    // workspace: xg (B*T*256 f32 = 16 MB) | hout (B*T*64 f32 = 4 MB)
    float* xg   = (float*)d_ws;
    float* hout = xg + (size_t)B_ * T_ * 256;

    encoder_kernel<<<B_ * T_ / 4, 256, 0, stream>>>(
        pressure, torque, frag,
        pw1, pb1, pw2, pb2, tw1, tb1, tw2, tb2,
        fw, fb, prw, prb, Wih, bih, bhh, xg);

    lstm_kernel<<<B_, 64, 0, stream>>>(xg, Whh, hout, out);

    head_kernel<<<B_ * T_ / 64, 256, 0, stream>>>(hout, hw, hb, out);
}

// Round 7
// 489.214 us; speedup vs baseline: 1.3347x; 1.2853x over previous
//
#include <hip/hip_runtime.h>
#include <math.h>

// Problem constants
#define B_   64
#define T_   256
#define W_   20
#define NP_  6
#define NT_  12
#define CC_  32      // CONV_CH
#define FD_  8       // FRAG_DIM
#define PR_  64      // PROJ

typedef float v2f __attribute__((ext_vector_type(2)));

// Pin a 2-register value into VGPRs (opaque def; float4 version does NOT
// compile on gfx950 — "tied indirect register inputs" — v2f does).
#define PIN2(x) asm volatile("" : "+v"(x))
// Wave-local LDS ordering: drain LDS ops only; no vmcnt, no barrier.
#define WAVE_SYNC() asm volatile("s_waitcnt lgkmcnt(0)" ::: "memory")
// Cross-wave barrier WITHOUT vmem drain: LDS ordering + s_barrier only.
#define LDS_BARRIER() asm volatile("s_waitcnt lgkmcnt(0)\n\ts_barrier" ::: "memory")

__device__ __forceinline__ float sigmoidf_(float x) {
    return 1.0f / (1.0f + __expf(-x));
}
__device__ __forceinline__ float tanhf_(float x) {
    x = fminf(fmaxf(x, -15.0f), 15.0f);
    float e = __expf(2.0f * x);
    return (e - 1.0f) / (e + 1.0f);
}

// -------------------------------------------------------------------------
// Kernel 1: encoders + fragility + projection + LSTM input-gate precompute.
// UNCHANGED (this round's change is the LSTM compile fix).
// -------------------------------------------------------------------------
__global__ __launch_bounds__(256, 3) void encoder_kernel(
    const float* __restrict__ pressure, const float* __restrict__ torque,
    const float* __restrict__ frag,
    const float* __restrict__ pw1, const float* __restrict__ pb1,
    const float* __restrict__ pw2, const float* __restrict__ pb2,
    const float* __restrict__ tw1, const float* __restrict__ tb1,
    const float* __restrict__ tw2, const float* __restrict__ tb2,
    const float* __restrict__ fw,  const float* __restrict__ fb,
    const float* __restrict__ prw, const float* __restrict__ prb,
    const float* __restrict__ Wih, const float* __restrict__ bih,
    const float* __restrict__ bhh,
    float* __restrict__ xg)             // (B,T,256) output
{
    const int tid  = threadIdx.x;       // 0..255
    const int wv   = tid >> 6;          // wave 0..3
    const int lane = tid & 63;
    const int bt   = blockIdx.x * 4 + wv;   // window id
    const int b    = bt >> 8;
    const int  o   = lane & 31;
    const bool isp = lane < 32;

    __shared__ float w2lds[64 * 97];                 // 24832 B, shared by all waves
    __shared__ __align__(16) float xwin4[4][360];    // per-wave window
    __shared__ __align__(16) float h14[4][1280];     // per-wave conv1 out
    __shared__ __align__(16) float catb4[4][72];
    __shared__ __align__(16) float featsh4[4][64];

    float* xwin   = xwin4[wv];
    float* h1     = h14[wv];
    float* catb   = catb4[wv];
    float* featsh = featsh4[wv];

    // ---- stage conv2 weights once per block (coalesced, rows 96 -> 97) ----
    for (int idx = tid; idx < CC_ * 96; idx += 256) {
        int row = idx / 96, col = idx - row * 96;
        w2lds[row * 97 + col] = pw2[idx];
    }
    for (int idx = tid; idx < CC_ * 96; idx += 256) {
        int row = idx / 96, col = idx - row * 96;
        w2lds[(32 + row) * 97 + col] = tw2[idx];
    }

    // ---- conv1 weights in regs, zero-padded to uniform 12 input rows ----
    float w1r[36];
    {
        const float* w1 = isp ? (pw1 + o * (NP_ * 3)) : (tw1 + o * (NT_ * 3));
        const int n3 = (isp ? NP_ : NT_) * 3;
        #pragma unroll
        for (int k = 0; k < 36; ++k) w1r[k] = (k < n3) ? w1[k] : 0.0f;
    }
    const float bz1 = isp ? pb1[o] : tb1[o];
    const float bz2 = isp ? pb2[o] : tb2[o];

    // ---- stage own window, transposing [w][i] -> [i][w] ----
    const float* pin = pressure + (size_t)bt * (W_ * NP_);
    for (int idx = lane; idx < W_ * NP_; idx += 64) {
        int w = idx / NP_, i = idx - w * NP_;
        xwin[i * 20 + w] = pin[idx];
    }
    const float* tin = torque + (size_t)bt * (W_ * NT_);
    for (int idx = lane; idx < W_ * NT_; idx += 64) {
        int w = idx / NT_, i = idx - w * NT_;
        xwin[120 + i * 20 + w] = tin[idx];
    }
    if (lane < FD_) catb[64 + lane] = fmaxf(frag[b] * fw[lane] + fb[lane], 0.0f);
    WAVE_SYNC();    // xwin visible within the wave (no vmcnt drain)

    // ---- conv1 (valid, K=3): uniform 12-row loop, weights in regs ----
    {
        const float* xin = xwin + (isp ? 0 : 120);
        float acc[18];
        #pragma unroll
        for (int l = 0; l < 18; ++l) acc[l] = bz1;
        #pragma unroll
        for (int i = 0; i < 12; ++i) {
            float4 xr4[5];
            const float4* xrow = (const float4*)(xin + i * 20);
            #pragma unroll
            for (int q = 0; q < 5; ++q) xr4[q] = xrow[q];     // broadcast b128
            const float* xr = (const float*)xr4;
            const float wk0 = w1r[i * 3 + 0], wk1 = w1r[i * 3 + 1], wk2 = w1r[i * 3 + 2];
            #pragma unroll
            for (int l = 0; l < 18; ++l)
                acc[l] += xr[l] * wk0 + xr[l + 1] * wk1 + xr[l + 2] * wk2;
        }
        float* h1o = h1 + (isp ? 0 : 640) + o * 20;
        #pragma unroll
        for (int l = 0; l < 18; ++l) h1o[l] = fmaxf(acc[l], 0.0f);
    }
    __syncthreads();   // the ONE real barrier: w2lds (cross-wave) + h1 ready

    // ---- conv2 (32->32, K=3) + relu + mean; weights from shared LDS ----
    {
        const float* h1i   = h1 + (isp ? 0 : 640);
        const float* w2row = w2lds + lane * 97;   // lane-distinct, 2/bank = free
        float s[16];
        #pragma unroll
        for (int l = 0; l < 16; ++l) s[l] = bz2;
        #pragma unroll 4
        for (int i = 0; i < 32; ++i) {
            float4 hr4[5];
            const float4* hrow = (const float4*)(h1i + i * 20);
            #pragma unroll
            for (int q = 0; q < 5; ++q) hr4[q] = hrow[q];     // broadcast b128
            const float* hr = (const float*)hr4;
            const float wk0 = w2row[i * 3 + 0], wk1 = w2row[i * 3 + 1], wk2 = w2row[i * 3 + 2];
            #pragma unroll
            for (int l = 0; l < 16; ++l)
                s[l] += hr[l] * wk0 + hr[l + 1] * wk1 + hr[l + 2] * wk2;
        }
        float m = 0.0f;
        #pragma unroll
        for (int l = 0; l < 16; ++l) m += fmaxf(s[l], 0.0f);
        catb[lane] = m * 0.0625f;
    }
    WAVE_SYNC();    // catb visible within the wave

    // ---- projection 72 -> 64, relu ----
    {
        float acc = prb[lane];
        const float4* w4 = (const float4*)(prw + lane * 72);
        const float4* c4 = (const float4*)catb;
        #pragma unroll
        for (int q = 0; q < 18; ++q) {
            float4 w = w4[q], cv = c4[q];
            acc += w.x * cv.x + w.y * cv.y + w.z * cv.z + w.w * cv.w;
        }
        featsh[lane] = fmaxf(acc, 0.0f);
    }
    WAVE_SYNC();    // featsh visible within the wave

    // ---- xg = feat @ Wih.T + bih + bhh ----
    {
        float4 fr[16];
        const float4* f4 = (const float4*)featsh;
        #pragma unroll
        for (int q = 0; q < 16; ++q) fr[q] = f4[q];
        float* xgrow = xg + (size_t)bt * 256;
        #pragma unroll
        for (int gi = 0; gi < 4; ++gi) {
            const int g = lane + 64 * gi;
            const float4* w4 = (const float4*)(Wih + (size_t)g * 64);
            float acc = bih[g] + bhh[g];
            #pragma unroll
            for (int q = 0; q < 16; ++q) {
                float4 w = w4[q];
                acc += w.x * fr[q].x + w.y * fr[q].y + w.z * fr[q].z + w.w * fr[q].w;
            }
            xgrow[g] = acc;
        }
    }
}

// -------------------------------------------------------------------------
// Kernel 2: LSTM — GATE-PER-WAVE. 64 blocks x 256 threads (4 waves).
// Wave g, lane j computes gate g of hidden unit j: weight set = 64 floats
// = 32 v2f = 64 VGPRs -> register-resident (pinned with the v2f form that
// compiles; float4 pinning does not on gfx950).
// One raw LDS-only barrier per step (no vmcnt drain); gbuf double-buffered;
// all waves redundantly compute activations (private c, private h copy).
// -------------------------------------------------------------------------
__global__ __launch_bounds__(256, 1) void lstm_kernel(
    const float* __restrict__ xg,     // (B,T,256), bias already included
    const float* __restrict__ Whh,    // (256,64)
    float* __restrict__ hout,         // (B,T,64)
    float* __restrict__ dout)         // full output buffer
{
    const int b   = blockIdx.x;
    const int tid = threadIdx.x;
    const int wv  = tid >> 6;         // gate index 0..3 (i,f,g,o)
    const int j   = tid & 63;         // hidden unit index

    __shared__ __align__(16) float hsw[4][64];   // per-wave private h copy
    __shared__ float gbuf[2][256];               // double-buffered gate exchange

    // weights: Whh row (wv*64+j), 64 floats = 32 v2f = 64 VGPRs, pinned
    v2f wr[32];
    {
        const v2f* row = (const v2f*)(Whh + (size_t)(wv * 64 + j) * 64);
        #pragma unroll
        for (int q = 0; q < 32; ++q) wr[q] = row[q];
        #pragma unroll
        for (int q = 0; q < 32; ++q) PIN2(wr[q]);
    }

    // xg element for this (gate, unit): xg[b][t][wv*64+j], stride 256 per step
    const float* xp = xg + (size_t)b * T_ * 256 + wv * 64 + j;
    float* hrow = hout + (size_t)b * T_ * 64;

    float c = 0.0f;
    hsw[wv][j] = 0.0f;
    WAVE_SYNC();                       // own-wave h copy initialized

    // 2-deep xg prefetch
    float xc = xp[0];
    float xn = xp[256];

    for (int t = 0; t < T_; ++t) {
        const int tp = (t + 2 < T_) ? (t + 2) : (T_ - 1);
        float xf = xp[tp * 256];       // stays in flight across the barrier

        // matvec slice: 32 packed FMAs, 4 split v2f accumulators
        v2f A0 = {xc, 0.0f}, A1 = {0.0f, 0.0f}, A2 = {0.0f, 0.0f}, A3 = {0.0f, 0.0f};
        const v2f* h2 = (const v2f*)hsw[wv];
        #pragma unroll
        for (int q = 0; q < 32; q += 4) {
            A0 += wr[q]     * h2[q];
            A1 += wr[q + 1] * h2[q + 1];
            A2 += wr[q + 2] * h2[q + 2];
            A3 += wr[q + 3] * h2[q + 3];
        }
        float* gb = gbuf[t & 1];
        gb[wv * 64 + j] = (A0.x + A0.y) + (A1.x + A1.y) + (A2.x + A2.y) + (A3.x + A3.y);
        LDS_BARRIER();                 // lgkmcnt(0)+s_barrier only; vmem in flight

        // every wave redundantly computes the cell update (consistent c copies)
        const float gi = gb[j], gf = gb[64 + j], gg = gb[128 + j], go = gb[192 + j];
        const float I = sigmoidf_(gi);
        const float F = sigmoidf_(gf);
        const float G = tanhf_(gg);
        const float O = sigmoidf_(go);
        c = F * c + I * G;
        const float h = O * tanhf_(c);

        hsw[wv][j] = h;                // own copy; no cross-wave dependency
        if (wv == 0) hrow[t * 64 + j] = h;   // store pipelines, never drained
        WAVE_SYNC();                   // own h write ordered before next read

        xc = xn; xn = xf;
    }

    if (wv == 0) {
        dout[B_ * T_ * 4 + b * 64 + j]           = hsw[0][j];  // hT
        dout[B_ * T_ * 4 + B_ * 64 + b * 64 + j] = c;          // cT
    }
}

// -------------------------------------------------------------------------
// Kernel 3: head (unchanged).
// -------------------------------------------------------------------------
__global__ __launch_bounds__(256) void head_kernel(
    const float* __restrict__ hout, const float* __restrict__ hw,
    const float* __restrict__ hb, float* __restrict__ out)
{
    const int blk = blockIdx.x;
    const int tid = threadIdx.x;

    __shared__ __align__(16) float hsh[64 * 68];
    __shared__ __align__(16) float wsh[256];
    __shared__ float bsh[4];

    const float4* s4 = (const float4*)(hout + (size_t)blk * 64 * 64);
    float4* d4 = (float4*)hsh;
    for (int q = tid; q < 1024; q += 256) {
        int row = q >> 4, col = q & 15;
        d4[row * 17 + col] = s4[q];
    }
    if (tid < 64) ((float4*)wsh)[tid] = ((const float4*)hw)[tid];
    if (tid < 4)  bsh[tid] = hb[tid];
    __syncthreads();

    const int r = tid >> 2, m = tid & 3;
    const float4* hv = (const float4*)(hsh + r * 68);
    const float4* wv = (const float4*)(wsh + m * 64);
    float acc = bsh[m];
    #pragma unroll
    for (int q = 0; q < 16; ++q) {
        float4 a = hv[q], w = wv[q];
        acc += a.x * w.x + a.y * w.y + a.z * w.z + a.w * w.w;
    }
    out[(size_t)blk * 256 + tid] = sigmoidf_(acc);
}

extern "C" void kernel_launch(void* const* d_in, const int* in_sizes, int n_in,
                              void* d_out, int out_size, void* d_ws, size_t ws_size,
                              hipStream_t stream) {
    const float* pressure = (const float*)d_in[0];
    const float* torque   = (const float*)d_in[1];
    const float* frag     = (const float*)d_in[2];
    const float* pw1 = (const float*)d_in[3];
    const float* pb1 = (const float*)d_in[4];
    const float* pw2 = (const float*)d_in[5];
    const float* pb2 = (const float*)d_in[6];
    const float* tw1 = (const float*)d_in[7];
    const float* tb1 = (const float*)d_in[8];
    const float* tw2 = (const float*)d_in[9];
    const float* tb2 = (const float*)d_in[10];
    const float* fw  = (const float*)d_in[11];
    const float* fb  = (const float*)d_in[12];
    const float* prw = (const float*)d_in[13];
    const float* prb = (const float*)d_in[14];
    const float* Wih = (const float*)d_in[15];
    const float* Whh = (const float*)d_in[16];
    const float* bih = (const float*)d_in[17];
    const float* bhh = (const float*)d_in[18];
    const float* hw  = (const float*)d_in[19];
    const float* hb  = (const float*)d_in[20];

    float* out = (float*)d_out;

    // workspace: xg (B*T*256 f32 = 16 MB) | hout (B*T*64 f32 = 4 MB)
    float* xg   = (float*)d_ws;
    float* hout = xg + (size_t)B_ * T_ * 256;

    encoder_kernel<<<B_ * T_ / 4, 256, 0, stream>>>(
        pressure, torque, frag,
        pw1, pb1, pw2, pb2, tw1, tb1, tw2, tb2,
        fw, fb, prw, prb, Wih, bih, bhh, xg);

    lstm_kernel<<<B_, 256, 0, stream>>>(xg, Whh, hout, out);

    head_kernel<<<B_ * T_ / 64, 256, 0, stream>>>(hout, hw, hb, out);
}